// Round 16
// baseline (217.305 us; speedup 1.0000x reference)
//
#include <hip/hip_runtime.h>

// LIF recurrence, T=4, TAU=1.0, THRESH=1.0.
// mem = mem + x[t]; spike = (mem - 1 > 0); mem = spike ? 0 : mem.
//
// v10: fully-streaming — NT loads AND NT stores. v9 (NT loads, cacheable
// stores) was the first real win: kernel ~77 -> ~67us (bench 227.7->217.3),
// confirming read-stream fragmentation from L3 half-hits was a real cost.
// Remaining gap to ideal (~43us): with loads bypassing cache, the output is
// now the only L2/L3 tenant — every store allocates a line and is evicted
// later as a capacity write-back at controller-unfriendly times, interleaved
// with the read stream. v8's "NT store == regular" was measured with
// CACHEABLE loads (L3 already hammered); NT/NT has never been run.
// NT stores: zero eviction churn, two clean decoupled DRAM streams (the
// fill-kernel regime). Single variable vs v9: store path.
// Signals: 55-60us => write-churn real, done. Neutral => store path free,
// declare structural ceiling next round. Worse => revert to v9 as final.

#define LIF_T 4
#define CHUNKS 4

typedef float f32x4 __attribute__((ext_vector_type(4)));

__device__ __forceinline__ f32x4 lif_step(f32x4& mem, f32x4 xt) {
    mem.x += xt.x;
    mem.y += xt.y;
    mem.z += xt.z;
    mem.w += xt.w;
    f32x4 sp;
    sp.x = (mem.x > 1.0f) ? 1.0f : 0.0f;
    sp.y = (mem.y > 1.0f) ? 1.0f : 0.0f;
    sp.z = (mem.z > 1.0f) ? 1.0f : 0.0f;
    sp.w = (mem.w > 1.0f) ? 1.0f : 0.0f;
    mem.x = (sp.x > 0.f) ? 0.f : mem.x;
    mem.y = (sp.y > 0.f) ? 0.f : mem.y;
    mem.z = (sp.z > 0.f) ? 0.f : mem.z;
    mem.w = (sp.w > 0.f) ? 0.f : mem.w;
    return sp;
}

__global__ __launch_bounds__(256) void
lif_spike_kernel(const float* __restrict__ x, float* __restrict__ out, int n_vec) {
    // Block b owns float4 indices [b*1024, b*1024+1024) of every plane:
    // 16KB-contiguous read/write windows per plane (v6 structure).
    const int base = blockIdx.x * (256 * CHUNKS) + threadIdx.x;
    const f32x4* __restrict__ xv = reinterpret_cast<const f32x4*>(x);
    f32x4* __restrict__ ov = reinterpret_cast<f32x4*>(out);

    if (base + (CHUNKS - 1) * 256 < n_vec) {
        // ---- fast path (exact cover in the bench shape: 2048*1024 == n_vec) ----
        f32x4 mem[CHUNKS];
#pragma unroll
        for (int c = 0; c < CHUNKS; ++c) mem[c] = (f32x4){0.f, 0.f, 0.f, 0.f};

#pragma unroll
        for (int t = 0; t < LIF_T; ++t) {
            const size_t p = (size_t)t * n_vec + base;
            f32x4 xt[CHUNKS];
            // NT loads: bypass L2/L3 -> full-miss, contiguous HBM read stream
#pragma unroll
            for (int c = 0; c < CHUNKS; ++c)
                xt[c] = __builtin_nontemporal_load(&xv[p + c * 256]);
#pragma unroll
            for (int c = 0; c < CHUNKS; ++c) {
                f32x4 sp = lif_step(mem[c], xt[c]);
                // NT store: no cache allocation, no eviction churn
                __builtin_nontemporal_store(sp, &ov[p + c * 256]);
            }
        }
    } else {
        // ---- tail path (not taken in the exact bench shape) ----
        f32x4 memc[CHUNKS];
#pragma unroll
        for (int c = 0; c < CHUNKS; ++c) memc[c] = (f32x4){0.f, 0.f, 0.f, 0.f};
#pragma unroll
        for (int t = 0; t < LIF_T; ++t) {
#pragma unroll
            for (int c = 0; c < CHUNKS; ++c) {
                int idx = base + c * 256;
                if (idx < n_vec) {
                    f32x4 xt = __builtin_nontemporal_load(&xv[(size_t)t * n_vec + idx]);
                    f32x4 sp = lif_step(memc[c], xt);
                    __builtin_nontemporal_store(sp, &ov[(size_t)t * n_vec + idx]);
                }
            }
        }
    }
}

extern "C" void kernel_launch(void* const* d_in, const int* in_sizes, int n_in,
                              void* d_out, int out_size, void* d_ws, size_t ws_size,
                              hipStream_t stream) {
    const float* x = (const float*)d_in[0];
    float* out = (float*)d_out;

    int n = out_size / LIF_T;      // elements per timestep (8,388,608)
    int n_vec = n / 4;             // float4 groups per timestep (2,097,152)

    const int block = 256;
    int grid = (n_vec + block * CHUNKS - 1) / (block * CHUNKS);  // 2048
    lif_spike_kernel<<<grid, block, 0, stream>>>(x, out, n_vec);
}